// Round 1
// baseline (475.145 us; speedup 1.0000x reference)
//
#include <hip/hip_runtime.h>

// MSPushPullLoss: B=16, C=16, labels 0..16, seg = b*17+lab, NSEG=272.
// Scales: (16,1024,1024) (16,512,512) (16,256,256); float4 vec counts per batch 2^18/2^16/2^14.
// R3: LDS fire-and-forget atomics (ds_add_f32) replace the serialized RMW chain;
//     bins shrink [17][256]->[17][128] (atomics make column sharing safe) so LDS
//     halves -> 8 blocks/CU; grid doubled to 2016 blocks so occupancy is real.
//     mean_kernel folded into pass2 prologue (tot_sum/cnt final after pass1).

#define NSEG 272
#define M_VAR 0.1f
#define TWO_M_DIST 3.0f

// Sub-blocks per batch per scale -- all scales give ~10.7 iters/thread.
#define SUB0 96
#define SUB1 24
#define SUB2 6
#define GRID_BLOCKS (16 * (SUB0 + SUB1 + SUB2))   // 2016 -> ~8 blocks/CU

__device__ __forceinline__ void gatomic_add(float* p, float v) {
  __hip_atomic_fetch_add(p, v, __ATOMIC_RELAXED, __HIP_MEMORY_SCOPE_AGENT);
}
// LDS atomic add, result unused -> ds_add_f32 (no return, no dependency chain).
__device__ __forceinline__ void latomic_add(float* p, float v) {
  __hip_atomic_fetch_add(p, v, __ATOMIC_RELAXED, __HIP_MEMORY_SCOPE_WORKGROUP);
}

struct Sel {
  const float4* f; const int4* g;
  int vbase, vend, stride, scale, batch;
};

__device__ __forceinline__ Sel pick(
    int b, int t,
    const float4* f0, const int4* g0,
    const float4* f1, const int4* g1,
    const float4* f2, const int4* g2) {
  Sel s;
  if (b < 16 * SUB0) {
    int batch = b / SUB0, sub = b - batch * SUB0;
    s.f = f0; s.g = g0; s.scale = 0; s.batch = batch;
    s.vbase = batch * 262144 + sub * 256 + t;
    s.vend  = (batch + 1) * 262144;
    s.stride = SUB0 * 256;
  } else if (b < 16 * (SUB0 + SUB1)) {
    int lb = b - 16 * SUB0; int batch = lb / SUB1, sub = lb - batch * SUB1;
    s.f = f1; s.g = g1; s.scale = 1; s.batch = batch;
    s.vbase = batch * 65536 + sub * 256 + t;
    s.vend  = (batch + 1) * 65536;
    s.stride = SUB1 * 256;
  } else {
    int lb = b - 16 * (SUB0 + SUB1); int batch = lb / SUB2, sub = lb - batch * SUB2;
    s.f = f2; s.g = g2; s.scale = 2; s.batch = batch;
    s.vbase = batch * 16384 + sub * 256 + t;
    s.vend  = (batch + 1) * 16384;
    s.stride = SUB2 * 256;
  }
  return s;
}

// ---------------- pass 1: per-(batch,label) sum + per-scale count ----------------
__global__ __launch_bounds__(256, 8) void pass1_kernel(
    const float4* __restrict__ f0, const int4* __restrict__ g0,
    const float4* __restrict__ f1, const int4* __restrict__ g1,
    const float4* __restrict__ f2, const int4* __restrict__ g2,
    float* __restrict__ tot_sum,   // [NSEG]
    float* __restrict__ cnt)       // [3][NSEG]
{
  __shared__ float ssum[17 * 128];  // 8704 B
  __shared__ float scnt[17 * 128];  // 8704 B  -> 17408 B total, 8 blocks/CU
  const int t = threadIdx.x;
  for (int i = t; i < 17 * 128; i += 256) { ssum[i] = 0.f; scnt[i] = 0.f; }
  __syncthreads();

  Sel s = pick(blockIdx.x, t, f0, g0, f1, g1, f2, g2);
  const int col = t & 127;           // lanes t and t+128 share a column (atomics make it safe)
  float* bs = ssum + col;
  float* bc = scnt + col;

  for (int v = s.vbase; v < s.vend; v += s.stride) {
    float4 fv = s.f[v];
    int4   gv = s.g[v];
    // label 0 = background -> bin 0 (never read); labels are 0..16 by construction.
    int lx = (int)min((unsigned)gv.x, 16u);
    int ly = (int)min((unsigned)gv.y, 16u);
    int lz = (int)min((unsigned)gv.z, 16u);
    int lw = (int)min((unsigned)gv.w, 16u);
    latomic_add(bs + lx * 128, fv.x);  latomic_add(bc + lx * 128, 1.f);
    latomic_add(bs + ly * 128, fv.y);  latomic_add(bc + ly * 128, 1.f);
    latomic_add(bs + lz * 128, fv.z);  latomic_add(bc + lz * 128, 1.f);
    latomic_add(bs + lw * 128, fv.w);  latomic_add(bc + lw * 128, 1.f);
  }

  // tree-reduce over columns: [17][128] -> [17][1]
  for (int sh = 6; sh >= 0; --sh) {
    __syncthreads();
    int off = 1 << sh;
    for (int i = t; i < 17 * off; i += 256) {
      int l = i >> sh, c = i & (off - 1);
      int a = l * 128 + c;
      ssum[a] += ssum[a + off];
      scnt[a] += scnt[a + off];
    }
  }
  __syncthreads();

  if (t >= 1 && t < 17) {
    float cv = scnt[t * 128];
    if (cv != 0.f) {
      gatomic_add(&tot_sum[s.batch * 17 + t], ssum[t * 128]);
      gatomic_add(&cnt[s.scale * NSEG + s.batch * 17 + t], cv);
    }
  }
}

// ---------------- pass 2: per-(scale,batch,label) pull sums ----------------
// Computes its own means in the prologue (tot_sum/cnt are final after pass1).
__global__ __launch_bounds__(256, 8) void pass2_kernel(
    const float4* __restrict__ f0, const int4* __restrict__ g0,
    const float4* __restrict__ f1, const int4* __restrict__ g1,
    const float4* __restrict__ f2, const int4* __restrict__ g2,
    const float* __restrict__ tot_sum,
    const float* __restrict__ cnt,
    float* __restrict__ pull)      // [3][NSEG]
{
  __shared__ float bins[17 * 128];  // 8704 B
  __shared__ float s_mean[17];
  const int t = threadIdx.x;

  Sel s = pick(blockIdx.x, t, f0, g0, f1, g1, f2, g2);

  for (int i = t; i < 17 * 128; i += 256) bins[i] = 0.f;
  if (t < 17) {
    int i = s.batch * 17 + t;
    float c = cnt[i] + cnt[NSEG + i] + cnt[2 * NSEG + i];
    s_mean[t] = tot_sum[i] / fmaxf(c, 1.f);
  }
  __syncthreads();

  const int col = t & 127;
  float* bb = bins + col;

  for (int v = s.vbase; v < s.vend; v += s.stride) {
    float4 fv = s.f[v];
    int4   gv = s.g[v];
    // invalid (label 0) falls into bin 0 with background mean -- bin 0 never read.
    {
      int l = (int)min((unsigned)gv.x, 16u);
      float d = fmaxf(fabsf(fv.x - s_mean[l]) - M_VAR, 0.f);
      latomic_add(bb + l * 128, d * d);
    }
    {
      int l = (int)min((unsigned)gv.y, 16u);
      float d = fmaxf(fabsf(fv.y - s_mean[l]) - M_VAR, 0.f);
      latomic_add(bb + l * 128, d * d);
    }
    {
      int l = (int)min((unsigned)gv.z, 16u);
      float d = fmaxf(fabsf(fv.z - s_mean[l]) - M_VAR, 0.f);
      latomic_add(bb + l * 128, d * d);
    }
    {
      int l = (int)min((unsigned)gv.w, 16u);
      float d = fmaxf(fabsf(fv.w - s_mean[l]) - M_VAR, 0.f);
      latomic_add(bb + l * 128, d * d);
    }
  }

  for (int sh = 6; sh >= 0; --sh) {
    __syncthreads();
    int off = 1 << sh;
    for (int i = t; i < 17 * off; i += 256) {
      int l = i >> sh, c = i & (off - 1);
      bins[l * 128 + c] += bins[l * 128 + c + off];
    }
  }
  __syncthreads();

  if (t >= 1 && t < 17) {
    float r = bins[t * 128];
    if (r != 0.f) gatomic_add(&pull[s.scale * NSEG + s.batch * 17 + t], r);
  }
}

// ---------------- finalize ----------------
__global__ __launch_bounds__(256) void finalize_kernel(
    const float* __restrict__ tot_sum,
    const float* __restrict__ cnt, const float* __restrict__ pull,
    float* __restrict__ out) {
  __shared__ float s_mean[NSEG];
  __shared__ unsigned char s_pres[NSEG];
  const int t = threadIdx.x;
  for (int i = t; i < NSEG; i += 256) {
    float c = cnt[i] + cnt[NSEG + i] + cnt[2 * NSEG + i];
    s_pres[i] = (c > 0.f) ? 1 : 0;
    s_mean[i] = tot_sum[i] / fmaxf(c, 1.f);
  }
  __syncthreads();

  float pull_v = 0.f, pull_n = 0.f, push_v = 0.f, push_n = 0.f;

  for (int i = t; i < NSEG; i += 256) {
    int lab = i - (i / 17) * 17;
    if (lab >= 1 && s_pres[i]) {
      float ps = 0.f;
      float c0 = cnt[i];            if (c0 > 0.f) ps += pull[i] / c0;
      float c1 = cnt[NSEG + i];     if (c1 > 0.f) ps += pull[NSEG + i] / c1;
      float c2 = cnt[2 * NSEG + i]; if (c2 > 0.f) ps += pull[2 * NSEG + i] / c2;
      pull_v += ps;
      pull_n += 1.f;
    }
  }

  {
    int b = t >> 4, ii = t & 15;
    int si = b * 17 + ii + 1;
    if (s_pres[si]) {
      float mi = s_mean[si];
      for (int j = 0; j < 16; ++j) {
        if (j == ii) continue;
        int sj = b * 17 + j + 1;
        if (s_pres[sj]) {
          float d = fmaxf(TWO_M_DIST - fabsf(mi - s_mean[sj]), 0.f);
          push_v += d * d;
          push_n += 1.f;
        }
      }
    }
  }

  #pragma unroll
  for (int o = 32; o > 0; o >>= 1) {
    pull_v += __shfl_down(pull_v, o);
    pull_n += __shfl_down(pull_n, o);
    push_v += __shfl_down(push_v, o);
    push_n += __shfl_down(push_n, o);
  }
  __shared__ float r[4][4];
  int wave = t >> 6;
  if ((t & 63) == 0) { r[wave][0] = pull_v; r[wave][1] = pull_n; r[wave][2] = push_v; r[wave][3] = push_n; }
  __syncthreads();
  if (t == 0) {
    float PV = 0, PN = 0, SV = 0, SN = 0;
    for (int w = 0; w < 4; ++w) { PV += r[w][0]; PN += r[w][1]; SV += r[w][2]; SN += r[w][3]; }
    out[0] = PV / fmaxf(PN, 1.f) + SV / fmaxf(SN, 1.f);
  }
}

extern "C" void kernel_launch(void* const* d_in, const int* in_sizes, int n_in,
                              void* d_out, int out_size, void* d_ws, size_t ws_size,
                              hipStream_t stream) {
  // setup_inputs() dict order: featmap0, gt0, featmap1, gt1, featmap2, gt2
  const float4* f0 = (const float4*)d_in[0];
  const int4*   g0 = (const int4*)  d_in[1];
  const float4* f1 = (const float4*)d_in[2];
  const int4*   g1 = (const int4*)  d_in[3];
  const float4* f2 = (const float4*)d_in[4];
  const int4*   g2 = (const int4*)  d_in[5];

  float* ws      = (float*)d_ws;
  float* tot_sum = ws;                // [NSEG]
  float* cnt     = ws + NSEG;         // [3][NSEG]
  float* pull    = ws + 4 * NSEG;     // [3][NSEG]

  hipMemsetAsync(d_ws, 0, 7 * NSEG * sizeof(float), stream);
  pass1_kernel<<<GRID_BLOCKS, 256, 0, stream>>>(f0, g0, f1, g1, f2, g2, tot_sum, cnt);
  pass2_kernel<<<GRID_BLOCKS, 256, 0, stream>>>(f0, g0, f1, g1, f2, g2, tot_sum, cnt, pull);
  finalize_kernel<<<1, 256, 0, stream>>>(tot_sum, cnt, pull, (float*)d_out);
}

// Round 2
// 229.090 us; speedup vs baseline: 2.0741x; 2.0741x over previous
//
#include <hip/hip_runtime.h>

// MSPushPullLoss: B=16, C=16, labels 0..16, seg = b*17+lab, NSEG=272.
// Scales: (16,1024,1024) (16,512,512) (16,256,256); float4 vec counts per batch 2^18/2^16/2^14.
// R4: NO LDS in hot loops.
//  - R3 post-mortem: ds_add_f32 LDS atomics are a serializing disaster (68->232us,
//    VALUBusy 1.9%). Reverted.
//  - pass1: per-thread VGPR histogram via fully-unrolled compare-select over 16 labels
//    (constant indices only -> registers). Wave shfl-reduce + tiny LDS + global atomics.
//  - pass2: fold 1/cnt into the pixel loop: acc += d^2 * inv_cnt[scale][lab] with
//    {mean,inv} gathered from a 17-entry read-only LDS table (17 banks, conflict-free).
//    Single scalar accumulator per thread; absent labels/label-0 have inv=0.

#define NSEG 272
#define M_VAR 0.1f
#define TWO_M_DIST 3.0f

// Sub-blocks per batch per scale (R2 grid: 1008 blocks ~= 4 blocks/CU, near-perfect balance).
#define SUB0 48
#define SUB1 12
#define SUB2 3
#define GRID_BLOCKS (16 * (SUB0 + SUB1 + SUB2))   // 1008

__device__ __forceinline__ void gatomic_add(float* p, float v) {
  __hip_atomic_fetch_add(p, v, __ATOMIC_RELAXED, __HIP_MEMORY_SCOPE_AGENT);
}

struct Sel {
  const float4* f; const int4* g;
  int vbase, vend, stride, scale, batch;
};

__device__ __forceinline__ Sel pick(
    int b, int t,
    const float4* f0, const int4* g0,
    const float4* f1, const int4* g1,
    const float4* f2, const int4* g2) {
  Sel s;
  if (b < 16 * SUB0) {
    int batch = b / SUB0, sub = b - batch * SUB0;
    s.f = f0; s.g = g0; s.scale = 0; s.batch = batch;
    s.vbase = batch * 262144 + sub * 256 + t;
    s.vend  = (batch + 1) * 262144;
    s.stride = SUB0 * 256;
  } else if (b < 16 * (SUB0 + SUB1)) {
    int lb = b - 16 * SUB0; int batch = lb / SUB1, sub = lb - batch * SUB1;
    s.f = f1; s.g = g1; s.scale = 1; s.batch = batch;
    s.vbase = batch * 65536 + sub * 256 + t;
    s.vend  = (batch + 1) * 65536;
    s.stride = SUB1 * 256;
  } else {
    int lb = b - 16 * (SUB0 + SUB1); int batch = lb / SUB2, sub = lb - batch * SUB2;
    s.f = f2; s.g = g2; s.scale = 2; s.batch = batch;
    s.vbase = batch * 16384 + sub * 256 + t;
    s.vend  = (batch + 1) * 16384;
    s.stride = SUB2 * 256;
  }
  return s;
}

// ---------------- pass 1: per-(batch,label) sum + per-scale count ----------------
__global__ __launch_bounds__(256, 4) void pass1_kernel(
    const float4* __restrict__ f0, const int4* __restrict__ g0,
    const float4* __restrict__ f1, const int4* __restrict__ g1,
    const float4* __restrict__ f2, const int4* __restrict__ g2,
    float* __restrict__ tot_sum,   // [NSEG]
    float* __restrict__ cnt)       // [3][NSEG]
{
  const int t = threadIdx.x;
  Sel s = pick(blockIdx.x, t, f0, g0, f1, g1, f2, g2);

  // Per-thread register histogram, labels 1..16 (label 0 = background, never read).
  float sum[17];
  int   cn[17];
  #pragma unroll
  for (int l = 1; l <= 16; ++l) { sum[l] = 0.f; cn[l] = 0; }

  int v = s.vbase;
  float4 fv = s.f[v];
  int4   gv = s.g[v];
  while (true) {
    int vn = v + s.stride;
    bool more = (vn < s.vend);
    float4 fn; int4 gn;
    if (more) { fn = s.f[vn]; gn = s.g[vn]; }   // prefetch next iter under this iter's VALU

    #pragma unroll
    for (int l = 1; l <= 16; ++l) {
      sum[l] += (gv.x == l) ? fv.x : 0.f;  cn[l] += (gv.x == l) ? 1 : 0;
      sum[l] += (gv.y == l) ? fv.y : 0.f;  cn[l] += (gv.y == l) ? 1 : 0;
      sum[l] += (gv.z == l) ? fv.z : 0.f;  cn[l] += (gv.z == l) ? 1 : 0;
      sum[l] += (gv.w == l) ? fv.w : 0.f;  cn[l] += (gv.w == l) ? 1 : 0;
    }

    if (!more) break;
    v = vn; fv = fn; gv = gn;
  }

  // wave shfl-reduce (64 lanes) then tiny LDS cross-wave combine
  __shared__ float rsum[4][16];
  __shared__ float rcnt[4][16];
  const int lane = t & 63, wave = t >> 6;
  #pragma unroll
  for (int l = 1; l <= 16; ++l) {
    float sv = sum[l];
    float cv = (float)cn[l];
    #pragma unroll
    for (int o = 32; o > 0; o >>= 1) {
      sv += __shfl_down(sv, o);
      cv += __shfl_down(cv, o);
    }
    if (lane == 0) { rsum[wave][l - 1] = sv; rcnt[wave][l - 1] = cv; }
  }
  __syncthreads();

  if (t < 16) {
    float sv = rsum[0][t] + rsum[1][t] + rsum[2][t] + rsum[3][t];
    float cv = rcnt[0][t] + rcnt[1][t] + rcnt[2][t] + rcnt[3][t];
    if (cv != 0.f) {
      gatomic_add(&tot_sum[s.batch * 17 + 1 + t], sv);
      gatomic_add(&cnt[s.scale * NSEG + s.batch * 17 + 1 + t], cv);
    }
  }
}

// ---------------- pass 2: pull accumulation with 1/cnt folded in ----------------
__global__ __launch_bounds__(256, 4) void pass2_kernel(
    const float4* __restrict__ f0, const int4* __restrict__ g0,
    const float4* __restrict__ f1, const int4* __restrict__ g1,
    const float4* __restrict__ f2, const int4* __restrict__ g2,
    const float* __restrict__ tot_sum,
    const float* __restrict__ cnt,
    float* __restrict__ pull_acc)  // [1] scalar: sum over all (b,l,s) of pull/cnt
{
  __shared__ float2 s_mi[17];  // {mean_l, inv_cnt[scale][l]}; 17 words/array -> 17 banks, conflict-free
  const int t = threadIdx.x;
  Sel s = pick(blockIdx.x, t, f0, g0, f1, g1, f2, g2);

  if (t < 17) {
    int i = s.batch * 17 + t;
    float c = cnt[i] + cnt[NSEG + i] + cnt[2 * NSEG + i];
    float mean = tot_sum[i] / fmaxf(c, 1.f);
    float cs = cnt[s.scale * NSEG + i];
    float inv = (t >= 1 && cs > 0.f) ? (1.f / cs) : 0.f;  // label 0 / absent -> 0 contribution
    s_mi[t] = make_float2(mean, inv);
  }
  __syncthreads();

  float acc = 0.f;
  int v = s.vbase;
  float4 fv = s.f[v];
  int4   gv = s.g[v];
  while (true) {
    int vn = v + s.stride;
    bool more = (vn < s.vend);
    float4 fn; int4 gn;
    if (more) { fn = s.f[vn]; gn = s.g[vn]; }

    {
      float2 mi = s_mi[min((unsigned)gv.x, 16u)];
      float d = fmaxf(fabsf(fv.x - mi.x) - M_VAR, 0.f);
      acc += d * d * mi.y;
    }
    {
      float2 mi = s_mi[min((unsigned)gv.y, 16u)];
      float d = fmaxf(fabsf(fv.y - mi.x) - M_VAR, 0.f);
      acc += d * d * mi.y;
    }
    {
      float2 mi = s_mi[min((unsigned)gv.z, 16u)];
      float d = fmaxf(fabsf(fv.z - mi.x) - M_VAR, 0.f);
      acc += d * d * mi.y;
    }
    {
      float2 mi = s_mi[min((unsigned)gv.w, 16u)];
      float d = fmaxf(fabsf(fv.w - mi.x) - M_VAR, 0.f);
      acc += d * d * mi.y;
    }

    if (!more) break;
    v = vn; fv = fn; gv = gn;
  }

  // block reduce single scalar
  #pragma unroll
  for (int o = 32; o > 0; o >>= 1) acc += __shfl_down(acc, o);
  __shared__ float racc[4];
  const int lane = t & 63, wave = t >> 6;
  if (lane == 0) racc[wave] = acc;
  __syncthreads();
  if (t == 0) gatomic_add(pull_acc, racc[0] + racc[1] + racc[2] + racc[3]);
}

// ---------------- finalize ----------------
__global__ __launch_bounds__(256) void finalize_kernel(
    const float* __restrict__ tot_sum, const float* __restrict__ cnt,
    const float* __restrict__ pull_acc, float* __restrict__ out) {
  __shared__ float s_mean[NSEG];
  __shared__ unsigned char s_pres[NSEG];
  const int t = threadIdx.x;
  for (int i = t; i < NSEG; i += 256) {
    float c = cnt[i] + cnt[NSEG + i] + cnt[2 * NSEG + i];
    s_pres[i] = (c > 0.f) ? 1 : 0;
    s_mean[i] = tot_sum[i] / fmaxf(c, 1.f);
  }
  __syncthreads();

  float pull_n = 0.f, push_v = 0.f, push_n = 0.f;

  for (int i = t; i < NSEG; i += 256) {
    int lab = i - (i / 17) * 17;
    if (lab >= 1 && s_pres[i]) pull_n += 1.f;
  }

  {
    int b = t >> 4, ii = t & 15;
    int si = b * 17 + ii + 1;
    if (s_pres[si]) {
      float mi = s_mean[si];
      for (int j = 0; j < 16; ++j) {
        if (j == ii) continue;
        int sj = b * 17 + j + 1;
        if (s_pres[sj]) {
          float d = fmaxf(TWO_M_DIST - fabsf(mi - s_mean[sj]), 0.f);
          push_v += d * d;
          push_n += 1.f;
        }
      }
    }
  }

  #pragma unroll
  for (int o = 32; o > 0; o >>= 1) {
    pull_n += __shfl_down(pull_n, o);
    push_v += __shfl_down(push_v, o);
    push_n += __shfl_down(push_n, o);
  }
  __shared__ float r[4][3];
  int wave = t >> 6;
  if ((t & 63) == 0) { r[wave][0] = pull_n; r[wave][1] = push_v; r[wave][2] = push_n; }
  __syncthreads();
  if (t == 0) {
    float PN = 0, SV = 0, SN = 0;
    for (int w = 0; w < 4; ++w) { PN += r[w][0]; SV += r[w][1]; SN += r[w][2]; }
    out[0] = pull_acc[0] / fmaxf(PN, 1.f) + SV / fmaxf(SN, 1.f);
  }
}

extern "C" void kernel_launch(void* const* d_in, const int* in_sizes, int n_in,
                              void* d_out, int out_size, void* d_ws, size_t ws_size,
                              hipStream_t stream) {
  // setup_inputs() dict order: featmap0, gt0, featmap1, gt1, featmap2, gt2
  const float4* f0 = (const float4*)d_in[0];
  const int4*   g0 = (const int4*)  d_in[1];
  const float4* f1 = (const float4*)d_in[2];
  const int4*   g1 = (const int4*)  d_in[3];
  const float4* f2 = (const float4*)d_in[4];
  const int4*   g2 = (const int4*)  d_in[5];

  float* ws       = (float*)d_ws;
  float* tot_sum  = ws;                 // [NSEG]
  float* cnt      = ws + NSEG;          // [3][NSEG]
  float* pull_acc = ws + 4 * NSEG;      // [1]

  hipMemsetAsync(d_ws, 0, (4 * NSEG + 1) * sizeof(float), stream);
  pass1_kernel<<<GRID_BLOCKS, 256, 0, stream>>>(f0, g0, f1, g1, f2, g2, tot_sum, cnt);
  pass2_kernel<<<GRID_BLOCKS, 256, 0, stream>>>(f0, g0, f1, g1, f2, g2, tot_sum, cnt, pull_acc);
  finalize_kernel<<<1, 256, 0, stream>>>(tot_sum, cnt, pull_acc, (float*)d_out);
}